// Round 16
// baseline (345.382 us; speedup 1.0000x reference)
//
#include <hip/hip_runtime.h>

#define BATCH 262144
#define MARGIN 1e-5f
#define LIST_CAP (1u<<20)

typedef __attribute__((ext_vector_type(8))) short short8;
typedef __attribute__((ext_vector_type(16))) float f32x16;

// ---------------- workspace layout (bytes) ----------------
// 0       : Rt64 f64[128][128]  Rt64[j*128+k] = R[k][j]      (131072)
// 131072  : img  u16: i1h[16384] i1l[16384] i2h[16384] i2l[16384] (131072)
// 262144  : counter u32
// 262912  : list u32[LIST_CAP]                                (4 MB)
// 4457216 : M64 f64[128][128]   I+A (exact)                   (131072)
// 4588288 : Y64 f64[128][128]   f32-GJ inverse                (131072)
// 4719360 : Yb  f64[128][128]   Newton intermediate           (131072)
// 4850432 : normg f32[BATCH]                                  (1048576)
// 5899008 : invg  f32[BATCH]                                  (1048576)

__device__ __forceinline__ unsigned f2bf(float f) {
  unsigned u = __float_as_uint(f);
  return (u + 0x7FFFu + ((u >> 16) & 1u)) >> 16;   // RTN-even bf16
}

// =======================================================================
// K_pre: block 0 = f32 GJ (spilled-but-fastest of 9 attempts, ~114 us,
// barrier/latency-pinned). Blocks 1..256 fill the bubble with row norms
// (hidden; pre-warms L3 with x). Y64 accuracy non-critical (kref polish).
// =======================================================================
__global__ __attribute__((amdgpu_waves_per_eu(4, 4))) __launch_bounds__(1024)
void kpre(const float* __restrict__ skew, const float* __restrict__ x,
          const float* __restrict__ mean, double* __restrict__ M64,
          double* __restrict__ Y64, float* __restrict__ normg,
          float* __restrict__ invg, unsigned int* __restrict__ counter)
{
  const int tid = threadIdx.x;

  if (blockIdx.x != 0) {
    const int b  = blockIdx.x - 1;
    const int wv = tid >> 6, ln = tid & 63;
    const int rowbase = b*1024 + wv*64;
    const float2 mv = *(const float2*)(mean + 2*ln);
    for (int i = 0; i < 64; ++i) {
      const int row = rowbase + i;
      float2 xv = *(const float2*)(x + (size_t)row*128 + 2*ln);
      float a = xv.x - mv.x, c = xv.y - mv.y;
      float sq = fmaf(a, a, c*c);
      sq += __shfl_xor(sq, 1);  sq += __shfl_xor(sq, 2);  sq += __shfl_xor(sq, 4);
      sq += __shfl_xor(sq, 8);  sq += __shfl_xor(sq, 16); sq += __shfl_xor(sq, 32);
      if (ln == 0) {
        float n = fmaxf(sqrtf(sq), 1e-8f);
        normg[row] = n;
        invg[row]  = 1.0f / n;
      }
    }
    return;
  }

  __shared__ float colk[2][128];
  __shared__ float pivrow[128];
  const int i = tid >> 3;
  const int s = tid & 7;
  if (tid == 0) *counter = 0;

  float M[16];
  #pragma unroll
  for (int e = 0; e < 16; ++e) {
    int j = s + 8*e;
    float v;
    if (i == j)      v = 1.0f;
    else if (i < j)  v =  skew[i*127 - (i*(i-1))/2 + (j - i - 1)];
    else             v = -skew[j*127 - (j*(j-1))/2 + (i - j - 1)];
    M[e] = v;
    M64[i*128 + j] = (double)v;     // exact I+A
  }
  if (s == 0) colk[0][i] = M[0];
  __syncthreads();

  for (int k = 0; k < 128; ++k) {
    const int p = k & 1, np = p ^ 1;
    const int ns = (k + 1) & 7, ne = (k + 1) >> 3;
    if (i == k) {
      float rec = 1.0f / colk[p][k];
      #pragma unroll
      for (int e = 0; e < 16; ++e) {
        int j = s + 8*e;
        float v = (j == k) ? 1.0f : M[e];
        v *= rec;
        M[e] = v;
        pivrow[j] = v;
      }
      if (s == ns && k < 127) colk[np][i] = M[ne];
    }
    __syncthreads();
    if (i != k) {
      float f = colk[p][i];
      #pragma unroll
      for (int e = 0; e < 16; ++e) {
        int j = s + 8*e;
        float v = (j == k) ? 0.0f : M[e];
        M[e] = fmaf(-f, pivrow[j], v);
      }
      if (s == ns && k < 127) colk[np][i] = M[ne];
    }
    __syncthreads();
  }

  #pragma unroll
  for (int e = 0; e < 16; ++e) {
    int j = s + 8*e;
    Y64[i*128 + j] = (double)M[e];
  }
}

// =======================================================================
// K_ref: one f64 Newton-Schulz step Yout = Yin*(2I - M64*Yin), per
// 16-column tile (8 blocks). final_pass: emit R = 2*Y2 - I as Rt64 +
// bf16-split fragment images.
// =======================================================================
__global__ __launch_bounds__(256, 2)
void kref(const double* __restrict__ M64, const double* __restrict__ Yin,
          double* __restrict__ Yout, double* __restrict__ Rt64,
          unsigned short* __restrict__ img, const int final_pass)
{
  __shared__ double Yc[128][17];
  __shared__ double T[128][17];
  const int t = threadIdx.x;
  const int c0 = blockIdx.x * 16;

  #pragma unroll
  for (int u = 0; u < 8; ++u) {
    int idx = u*256 + t;
    int row = idx >> 4, cc = idx & 15;
    Yc[row][cc] = Yin[row*128 + c0 + cc];
  }
  __syncthreads();

  const int m = t >> 1;
  const int h = (t & 1) * 8;

  double a0=0,a1=0,a2=0,a3=0,a4=0,a5=0,a6=0,a7=0;
  for (int j = 0; j < 128; ++j) {
    double mv = M64[m*128 + j];
    a0 = fma(mv, Yc[j][h+0], a0);  a1 = fma(mv, Yc[j][h+1], a1);
    a2 = fma(mv, Yc[j][h+2], a2);  a3 = fma(mv, Yc[j][h+3], a3);
    a4 = fma(mv, Yc[j][h+4], a4);  a5 = fma(mv, Yc[j][h+5], a5);
    a6 = fma(mv, Yc[j][h+6], a6);  a7 = fma(mv, Yc[j][h+7], a7);
  }
  T[m][h+0]=a0; T[m][h+1]=a1; T[m][h+2]=a2; T[m][h+3]=a3;
  T[m][h+4]=a4; T[m][h+5]=a5; T[m][h+6]=a6; T[m][h+7]=a7;
  __syncthreads();

  double b0=0,b1=0,b2=0,b3=0,b4=0,b5=0,b6=0,b7=0;
  for (int j = 0; j < 128; ++j) {
    double yv = Yin[m*128 + j];
    b0 = fma(yv, T[j][h+0], b0);  b1 = fma(yv, T[j][h+1], b1);
    b2 = fma(yv, T[j][h+2], b2);  b3 = fma(yv, T[j][h+3], b3);
    b4 = fma(yv, T[j][h+4], b4);  b5 = fma(yv, T[j][h+5], b5);
    b6 = fma(yv, T[j][h+6], b6);  b7 = fma(yv, T[j][h+7], b7);
  }

  double y2[8] = { 2.0*Yc[m][h+0]-b0, 2.0*Yc[m][h+1]-b1, 2.0*Yc[m][h+2]-b2,
                   2.0*Yc[m][h+3]-b3, 2.0*Yc[m][h+4]-b4, 2.0*Yc[m][h+5]-b5,
                   2.0*Yc[m][h+6]-b6, 2.0*Yc[m][h+7]-b7 };

  if (!final_pass) {
    #pragma unroll
    for (int c = 0; c < 8; ++c) Yout[m*128 + c0 + h + c] = y2[c];
  } else {
    #pragma unroll
    for (int c = 0; c < 8; ++c) {
      const int i = m, j = c0 + h + c;
      double v = 2.0*y2[c] - ((i == j) ? 1.0 : 0.0);    // R[i][j]
      Rt64[j*128 + i] = v;
      float r32 = (float)v;
      unsigned hh = f2bf(r32);
      unsigned ll = f2bf(r32 - __uint_as_float(hh << 16));
      int off1 = (((i>>5)*8 + (j>>4))*64 + ((((j>>3)&1)<<5) | (i&31)))*8 + (j&7);
      img[off1]          = (unsigned short)hh;
      img[16384 + off1]  = (unsigned short)ll;
      int off2 = (((j>>5)*8 + (i>>4))*64 + ((((i>>3)&1)<<5) | (j&31)))*8 + (i&7);
      img[32768 + off2]  = (unsigned short)hh;
      img[49152 + off2]  = (unsigned short)ll;
    }
  }
}

// =======================================================================
// K_main occupancy push v3 (r11 failed via waves3+full-B spill, r14 via
// (256,4) 128-budget spill -- this keeps budget 170 and SHRINKS need):
// B1 in regs (64), B2 STREAMED from L2 in phase C (anti-LICM opaque ptr
// so LLVM can't hoist it back into 64 regs), X/Q single-buffered (lgkm
// barriers make dbuf redundant -- every conflicting write/read pair is
// separated by a drain barrier in all wave orderings). Need ~164 regs
// <= 512/3; LDS 33.8 KB -> 3 blocks/CU (12 waves, was 8).
// =======================================================================
#define MM3(ACC, XH, XL, BH, BL)                                        \
  ACC = __builtin_amdgcn_mfma_f32_32x32x16_bf16(XH, BH, ACC, 0, 0, 0);  \
  ACC = __builtin_amdgcn_mfma_f32_32x32x16_bf16(XL, BH, ACC, 0, 0, 0);  \
  ACC = __builtin_amdgcn_mfma_f32_32x32x16_bf16(XH, BL, ACC, 0, 0, 0);

#define LGKM_BAR()                                                      \
  asm volatile("s_waitcnt lgkmcnt(0)" ::: "memory");                    \
  __builtin_amdgcn_s_barrier();                                         \
  __builtin_amdgcn_sched_barrier(0);

__global__ __launch_bounds__(256, 3)
void kmain(const float* __restrict__ x, const float* __restrict__ mean,
           const float* __restrict__ cent, const unsigned short* __restrict__ img,
           const float* __restrict__ normg, const float* __restrict__ invg,
           float* __restrict__ out,
           unsigned int* __restrict__ counter, unsigned int* __restrict__ list)
{
  __shared__ __align__(16) unsigned short Xh[32*128];   // 8 KB (swizzled)
  __shared__ __align__(16) unsigned short Xl[32*128];
  __shared__ __align__(16) unsigned short Qh[32*128];
  __shared__ __align__(16) unsigned short Ql[32*128];
  __shared__ float norms[4][32];     // per-wave private
  __shared__ float invs[4][32];

  const int tid = threadIdx.x, lane = tid & 63, w = tid >> 6;
  const int al = lane & 31, ah = lane >> 5;

  // B1 (mm1 B) resident in registers; B2 streamed per chunk from L2.
  short8 B1h[8], B1l[8];
  #pragma unroll
  for (int t = 0; t < 8; ++t) {
    size_t o = (size_t)((w*8 + t)*64 + lane)*8;
    B1h[t] = *(const short8*)(img +         o);
    B1l[t] = *(const short8*)(img + 16384 + o);
  }

  const float c0 = cent[0], c1 = cent[1], c2 = cent[2], c3 = cent[3];
  const float c4 = cent[4], c5 = cent[5], c6 = cent[6], c7 = cent[7];
  const float mid0 = 0.5f*(c0+c1), mid1 = 0.5f*(c1+c2), mid2 = 0.5f*(c2+c3),
              mid3 = 0.5f*(c3+c4), mid4 = 0.5f*(c4+c5), mid5 = 0.5f*(c5+c6),
              mid6 = 0.5f*(c6+c7);
  unsigned qt0, qt1, qt2, qt3, qt4, qt5, qt6, qt7;
  {
    #define PS(C, QT) { unsigned h = f2bf(C); float hf = __uint_as_float(h<<16); \
                        QT = (h<<16) | f2bf((C) - hf); }
    PS(c0,qt0) PS(c1,qt1) PS(c2,qt2) PS(c3,qt3)
    PS(c4,qt4) PS(c5,qt5) PS(c6,qt6) PS(c7,qt7)
    #undef PS
  }

  const float2 mean2 = *(const float2*)(mean + 2*lane);
  const float meanv = mean[w*32 + al];

  const int row0 = blockIdx.x * 256;

  float2 xpf[8];
  #pragma unroll
  for (int rr = 0; rr < 8; ++rr)
    xpf[rr] = *(const float2*)(x + (size_t)(row0 + w*8 + rr)*128 + 2*lane);

  for (int ch = 0; ch < 8; ++ch) {
    const int chb = row0 + ch*32;

    // ---- Phase A: next-chunk loads; norm load; cvt_pk split -> X ----
    if (ah == 0) {                         // lanes 0..31: per-wave norm bcast
      norms[w][al] = normg[chb + al];
      invs[w][al]  = invg[chb + al];
    }
    float2 xn[8];
    if (ch < 7) {
      #pragma unroll
      for (int rr = 0; rr < 8; ++rr)
        xn[rr] = *(const float2*)(x + (size_t)(chb + 32 + w*8 + rr)*128 + 2*lane);
    }
    #pragma unroll
    for (int rr = 0; rr < 8; ++rr) {
      const int r = w*8 + rr;
      float a = xpf[rr].x - mean2.x;
      float b = xpf[rr].y - mean2.y;
      unsigned ph, pl;
      asm("v_cvt_pk_bf16_f32 %0, %1, %2" : "=v"(ph) : "v"(a), "v"(b));
      float ha = __uint_as_float(ph << 16);
      float hb = __uint_as_float(ph & 0xFFFF0000u);
      float ra = a - ha, rb = b - hb;
      asm("v_cvt_pk_bf16_f32 %0, %1, %2" : "=v"(pl) : "v"(ra), "v"(rb));
      unsigned off = ((unsigned)(r*256 + 4*lane)) ^ (((unsigned)(r & 7)) << 4);
      *(unsigned*)((char*)Xh + off) = ph;
      *(unsigned*)((char*)Xl + off) = pl;
    }
    #pragma unroll
    for (int rr = 0; rr < 8; ++rr) xpf[rr] = xn[rr];
    LGKM_BAR();                                       // bar1: X+norms ready

    // ---- Phase B: mm1 (X x B1 regs), quantize, write Q ----
    f32x16 accA, accB;
    #pragma unroll
    for (int g = 0; g < 16; ++g) { accA[g] = 0.0f; accB[g] = 0.0f; }
    __builtin_amdgcn_s_setprio(1);
    #pragma unroll
    for (int t = 0; t < 8; ++t) {
      unsigned fb = ((unsigned)(al*256 + t*32 + ah*16)) ^ (((unsigned)(al & 7)) << 4);
      short8 xh = *(const short8*)((const char*)Xh + fb);
      short8 xl = *(const short8*)((const char*)Xl + fb);
      if (t & 1) { MM3(accB, xh, xl, B1h[t], B1l[t]); }
      else       { MM3(accA, xh, xl, B1h[t], B1l[t]); }
    }
    __builtin_amdgcn_s_setprio(0);
    #pragma unroll
    for (int g = 0; g < 16; ++g) accA[g] += accB[g];

    unsigned qp[16];
    unsigned flags = 0;
    #pragma unroll
    for (int g = 0; g < 16; ++g) {
      const int r = (g & 3) + 8*(g >> 2) + 4*ah;
      float xr = accA[g] * invs[w][r];
      unsigned q = qt0;
      q = (xr > mid0) ? qt1 : q;  q = (xr > mid1) ? qt2 : q;
      q = (xr > mid2) ? qt3 : q;  q = (xr > mid3) ? qt4 : q;
      q = (xr > mid4) ? qt5 : q;  q = (xr > mid5) ? qt6 : q;
      q = (xr > mid6) ? qt7 : q;
      float dm = fabsf(xr - mid0);
      dm = fminf(dm, fabsf(xr - mid1)); dm = fminf(dm, fabsf(xr - mid2));
      dm = fminf(dm, fabsf(xr - mid3)); dm = fminf(dm, fabsf(xr - mid4));
      dm = fminf(dm, fabsf(xr - mid5)); dm = fminf(dm, fabsf(xr - mid6));
      qp[g] = q;
      flags |= (dm < MARGIN) ? (1u << g) : 0u;
    }
    #pragma unroll
    for (int g = 0; g < 16; ++g) {
      const int rq = (g & 3) + 8*(g >> 2) + 4*ah;
      unsigned off = ((unsigned)(rq*256 + (w*32 + al)*2)) ^ (((unsigned)(rq & 7)) << 4);
      *(unsigned short*)((char*)Qh + off) = (unsigned short)(qp[g] >> 16);
      *(unsigned short*)((char*)Ql + off) = (unsigned short)(qp[g] & 0xFFFFu);
    }
    if (__builtin_amdgcn_ballot_w64(flags != 0)) {   // rare path
      #pragma unroll
      for (int g = 0; g < 16; ++g) {
        unsigned long long b = __ballot((flags >> g) & 1u);
        if (b) {
          const int rq = (g & 3) + 8*(g >> 2) + 4*ah;
          unsigned base = 0;
          if (lane == 0) base = atomicAdd(counter, (unsigned)__popcll(b));
          base = (unsigned)__shfl((int)base, 0);
          if ((flags >> g) & 1u) {
            unsigned pp = base + (unsigned)__popcll(b & ((1ull << lane) - 1ull));
            if (pp < LIST_CAP) list[pp] = (unsigned)(chb + rq);
          }
        }
      }
    }
    LGKM_BAR();                                       // bar2: Q ready

    // ---- Phase C: mm2 (Q x B2 streamed from L2), scale + store ----
    // Opaque pointer per chunk: blocks LICM from hoisting the 32
    // loop-invariant B2 loads into registers (would recreate the
    // 128-reg footprint and spill at the 170 budget).
    const unsigned short* i2p = img;
    asm volatile("" : "+v"(i2p));
    f32x16 acc2, acc3;
    #pragma unroll
    for (int g = 0; g < 16; ++g) { acc2[g] = 0.0f; acc3[g] = 0.0f; }
    __builtin_amdgcn_s_setprio(1);
    #pragma unroll
    for (int t = 0; t < 8; ++t) {
      size_t o = (size_t)((w*8 + t)*64 + lane)*8;
      short8 bh = *(const short8*)(i2p + 32768 + o);
      short8 bl = *(const short8*)(i2p + 49152 + o);
      unsigned fb = ((unsigned)(al*256 + t*32 + ah*16)) ^ (((unsigned)(al & 7)) << 4);
      short8 xh = *(const short8*)((const char*)Qh + fb);
      short8 xl = *(const short8*)((const char*)Ql + fb);
      if (t & 1) { MM3(acc3, xh, xl, bh, bl); }
      else       { MM3(acc2, xh, xl, bh, bl); }
    }
    __builtin_amdgcn_s_setprio(0);

    #pragma unroll
    for (int g = 0; g < 16; ++g) {
      const int rq = (g & 3) + 8*(g >> 2) + 4*ah;
      float o = fmaf(acc2[g] + acc3[g], norms[w][rq], meanv);
      out[(size_t)(chb + rq)*128 + w*32 + al] = o;
    }
  }
}

// =======================================================================
// K_fix: exact f64 recompute of rows with any element within MARGIN of
// a quantization midpoint. One wave per row; overwrites out. Unchanged.
// =======================================================================
__global__ __launch_bounds__(256)
void kfix(const float* __restrict__ x, const float* __restrict__ mean,
          const float* __restrict__ cent, const double* __restrict__ Rt64,
          float* __restrict__ out,
          const unsigned int* __restrict__ counter,
          const unsigned int* __restrict__ list)
{
  __shared__ double xs[4][128];
  __shared__ double qs[4][128];
  const int tid = threadIdx.x, lane = tid & 63, w = tid >> 6;

  unsigned cnt = *counter;
  if (cnt > LIST_CAP) cnt = LIST_CAP;

  const double cc0 = (double)cent[0], cc1 = (double)cent[1], cc2 = (double)cent[2],
               cc3 = (double)cent[3], cc4 = (double)cent[4], cc5 = (double)cent[5],
               cc6 = (double)cent[6], cc7 = (double)cent[7];
  const double m0 = 0.5*(cc0+cc1), m1 = 0.5*(cc1+cc2), m2 = 0.5*(cc2+cc3),
               m3 = 0.5*(cc3+cc4), m4 = 0.5*(cc4+cc5), m5 = 0.5*(cc5+cc6),
               m6 = 0.5*(cc6+cc7);

  const unsigned gw = blockIdx.x*4 + w, stride = gridDim.x*4;
  for (unsigned e = gw; e < cnt; e += stride) {
    const int row = (int)list[e];
    const float* xr = x + (size_t)row*128;
    const int j0 = 2*lane;

    double a = (double)xr[j0]   - (double)mean[j0];
    double b = (double)xr[j0+1] - (double)mean[j0+1];
    double s = a*a + b*b;
    s += __shfl_xor(s, 1);  s += __shfl_xor(s, 2);  s += __shfl_xor(s, 4);
    s += __shfl_xor(s, 8);  s += __shfl_xor(s, 16); s += __shfl_xor(s, 32);
    double n = sqrt(s);
    if (n < 1e-8) n = 1e-8;
    double inv = 1.0 / n;
    xs[w][j0]   = a * inv;
    xs[w][j0+1] = b * inv;
    asm volatile("s_waitcnt lgkmcnt(0)" ::: "memory");

    double acc0 = 0.0, acc1 = 0.0;
    for (int j = 0; j < 128; ++j) {
      double xj = xs[w][j];
      acc0 = fma(xj, Rt64[j*128 + j0],     acc0);
      acc1 = fma(xj, Rt64[j*128 + j0 + 1], acc1);
    }
    double q0 = cc0;
    q0 = (acc0 > m0) ? cc1 : q0;  q0 = (acc0 > m1) ? cc2 : q0;
    q0 = (acc0 > m2) ? cc3 : q0;  q0 = (acc0 > m3) ? cc4 : q0;
    q0 = (acc0 > m4) ? cc5 : q0;  q0 = (acc0 > m5) ? cc6 : q0;
    q0 = (acc0 > m6) ? cc7 : q0;
    double q1 = cc0;
    q1 = (acc1 > m0) ? cc1 : q1;  q1 = (acc1 > m1) ? cc2 : q1;
    q1 = (acc1 > m2) ? cc3 : q1;  q1 = (acc1 > m3) ? cc4 : q1;
    q1 = (acc1 > m4) ? cc5 : q1;  q1 = (acc1 > m5) ? cc6 : q1;
    q1 = (acc1 > m6) ? cc7 : q1;
    qs[w][j0]   = q0;
    qs[w][j0+1] = q1;
    asm volatile("s_waitcnt lgkmcnt(0)" ::: "memory");

    double o0 = 0.0, o1 = 0.0;
    for (int k = 0; k < 128; ++k) {
      double qk = qs[w][k];
      o0 = fma(qk, Rt64[j0*128 + k],       o0);
      o1 = fma(qk, Rt64[(j0+1)*128 + k],   o1);
    }
    out[(size_t)row*128 + j0]   = (float)fma(o0, n, (double)mean[j0]);
    out[(size_t)row*128 + j0+1] = (float)fma(o1, n, (double)mean[j0+1]);
  }
}

// =======================================================================
extern "C" void kernel_launch(void* const* d_in, const int* in_sizes, int n_in,
                              void* d_out, int out_size, void* d_ws, size_t ws_size,
                              hipStream_t stream)
{
  (void)in_sizes; (void)n_in; (void)out_size; (void)ws_size;
  const float* x    = (const float*)d_in[0];
  const float* skew = (const float*)d_in[1];
  const float* cent = (const float*)d_in[2];
  const float* mean = (const float*)d_in[3];
  float* out = (float*)d_out;

  char* ws = (char*)d_ws;
  double*         Rt64  = (double*)(ws);
  unsigned short* img   = (unsigned short*)(ws + 131072);
  unsigned int*   cntr  = (unsigned int*)(ws + 262144);
  unsigned int*   list  = (unsigned int*)(ws + 262912);
  double*         M64   = (double*)(ws + 4457216);
  double*         Y64   = (double*)(ws + 4588288);
  double*         Yb    = (double*)(ws + 4719360);
  float*          normg = (float*)(ws + 4850432);
  float*          invg  = (float*)(ws + 5899008);

  kpre <<<dim3(257),  dim3(1024), 0, stream>>>(skew, x, mean, M64, Y64,
                                               normg, invg, cntr);
  kref <<<dim3(8),    dim3(256),  0, stream>>>(M64, Y64, Yb, Rt64, img, 0);
  kref <<<dim3(8),    dim3(256),  0, stream>>>(M64, Yb, Y64, Rt64, img, 1);
  kmain<<<dim3(1024), dim3(256),  0, stream>>>(x, mean, cent, img, normg, invg,
                                               out, cntr, list);
  kfix <<<dim3(256),  dim3(256),  0, stream>>>(x, mean, cent, Rt64, out, cntr, list);
}

// Round 17
// 275.263 us; speedup vs baseline: 1.2547x; 1.2547x over previous
//
#include <hip/hip_runtime.h>

#define BATCH 262144
#define MARGIN 1e-5f
#define LIST_CAP (1u<<20)

typedef __attribute__((ext_vector_type(8))) short short8;
typedef __attribute__((ext_vector_type(16))) float f32x16;

// ---------------- workspace layout (bytes) ----------------
// 0       : Rt64 f64[128][128]  Rt64[j*128+k] = R[k][j]      (131072)
// 131072  : img  u16: i1h[16384] i1l[16384] i2h[16384] i2l[16384] (131072)
// 262144  : counter u32
// 262912  : list u32[LIST_CAP]                                (4 MB)
// 4457216 : M64 f64[128][128]   I+A (exact)                   (131072)
// 4588288 : Y64 f64[128][128]   f32-GJ inverse                (131072)
// 4719360 : Yb  f64[128][128]   Newton intermediate           (131072)
// 4850432 : normg f32[BATCH]                                  (1048576)
// 5899008 : invg  f32[BATCH]                                  (1048576)

__device__ __forceinline__ unsigned f2bf(float f) {
  unsigned u = __float_as_uint(f);
  return (u + 0x7FFFu + ((u >> 16) & 1u)) >> 16;   // RTN-even bf16
}

// =======================================================================
// K_pre: block 0 = f32 GJ, 1-barrier/iter variant. r15 evidence (VGPR 52)
// shows the f32 state is register-resident in this codegen context (norm
// branch present), so the 114 us was barrier+LDS-issue pinning:
//  - 1 barrier/iter: row k+1 publishes its post-elimination raw row
//    during iter k; rec computed redundantly by all threads.
//  - contiguous ownership j = s*16+e with bank-padded praw[2][8][20]
//    (stride 20 -> 8 distinct bank groups): praw traffic = 4x float4
//    instead of 16 scalar ds_read.
// Blocks 1..256 fill the bubble with row norms (pre-warms L3 with x).
// Y64 accuracy non-critical (kref f64 Newton polish squares residual).
// =======================================================================
__global__ __attribute__((amdgpu_waves_per_eu(4, 4))) __launch_bounds__(1024)
void kpre(const float* __restrict__ skew, const float* __restrict__ x,
          const float* __restrict__ mean, double* __restrict__ M64,
          double* __restrict__ Y64, float* __restrict__ normg,
          float* __restrict__ invg, unsigned int* __restrict__ counter)
{
  const int tid = threadIdx.x;

  if (blockIdx.x != 0) {
    const int b  = blockIdx.x - 1;
    const int wv = tid >> 6, ln = tid & 63;
    const int rowbase = b*1024 + wv*64;
    const float2 mv = *(const float2*)(mean + 2*ln);
    for (int i = 0; i < 64; ++i) {
      const int row = rowbase + i;
      float2 xv = *(const float2*)(x + (size_t)row*128 + 2*ln);
      float a = xv.x - mv.x, c = xv.y - mv.y;
      float sq = fmaf(a, a, c*c);
      sq += __shfl_xor(sq, 1);  sq += __shfl_xor(sq, 2);  sq += __shfl_xor(sq, 4);
      sq += __shfl_xor(sq, 8);  sq += __shfl_xor(sq, 16); sq += __shfl_xor(sq, 32);
      if (ln == 0) {
        float n = fmaxf(sqrtf(sq), 1e-8f);
        normg[row] = n;
        invg[row]  = 1.0f / n;
      }
    }
    return;
  }

  __shared__ float colk[2][128];
  __shared__ float praw[2][8][20];       // padded: stride 20 floats
  const int i = tid >> 3;                // row
  const int s = tid & 7;                 // owns cols j = s*16 + e
  if (tid == 0) *counter = 0;

  float M[16];
  #pragma unroll
  for (int e = 0; e < 16; ++e) {
    int j = s*16 + e;
    float v;
    if (i == j)      v = 1.0f;
    else if (i < j)  v =  skew[i*127 - (i*(i-1))/2 + (j - i - 1)];
    else             v = -skew[j*127 - (j*(j-1))/2 + (i - j - 1)];
    M[e] = v;
    M64[i*128 + j] = (double)v;          // exact I+A
  }
  // prologue: raw column 0 (owner s=0,e=0) and raw row 0
  if (s == 0) colk[0][i] = M[0];
  if (i == 0) {
    *(float4*)&praw[0][s][0]  = make_float4(M[0],  M[1],  M[2],  M[3]);
    *(float4*)&praw[0][s][4]  = make_float4(M[4],  M[5],  M[6],  M[7]);
    *(float4*)&praw[0][s][8]  = make_float4(M[8],  M[9],  M[10], M[11]);
    *(float4*)&praw[0][s][12] = make_float4(M[12], M[13], M[14], M[15]);
  }
  __syncthreads();

  for (int k = 0; k < 128; ++k) {
    const int p = k & 1, np = p ^ 1;
    const int kp1 = k + 1;
    const int ns = kp1 >> 4, ne = kp1 & 15;   // kp1=128 -> ns=8: no publish
    const float rec = 1.0f / colk[p][k];      // redundant in all threads
    if (i == k) {
      #pragma unroll
      for (int e = 0; e < 16; ++e) {
        int j = s*16 + e;
        M[e] = (j == k) ? rec : M[e] * rec;   // final scaled pivot row
      }
    } else {
      const float t = colk[p][i] * rec;
      float4 p0 = *(float4*)&praw[p][s][0];
      float4 p1 = *(float4*)&praw[p][s][4];
      float4 p2 = *(float4*)&praw[p][s][8];
      float4 p3 = *(float4*)&praw[p][s][12];
      float pr[16] = { p0.x,p0.y,p0.z,p0.w, p1.x,p1.y,p1.z,p1.w,
                       p2.x,p2.y,p2.z,p2.w, p3.x,p3.y,p3.z,p3.w };
      #pragma unroll
      for (int e = 0; e < 16; ++e) {
        int j = s*16 + e;
        M[e] = (j == k) ? (0.0f - t) : fmaf(-t, pr[e], M[e]);
      }
      if (i == kp1) {                    // publish next raw pivot row
        *(float4*)&praw[np][s][0]  = make_float4(M[0],  M[1],  M[2],  M[3]);
        *(float4*)&praw[np][s][4]  = make_float4(M[4],  M[5],  M[6],  M[7]);
        *(float4*)&praw[np][s][8]  = make_float4(M[8],  M[9],  M[10], M[11]);
        *(float4*)&praw[np][s][12] = make_float4(M[12], M[13], M[14], M[15]);
      }
    }
    if (s == ns) colk[np][i] = M[ne];    // r15's proven in-branch idiom
    __syncthreads();
  }

  #pragma unroll
  for (int e = 0; e < 16; ++e) {
    int j = s*16 + e;
    Y64[i*128 + j] = (double)M[e];
  }
}

// =======================================================================
// K_ref: one f64 Newton-Schulz step Yout = Yin*(2I - M64*Yin), per
// 16-column tile (8 blocks). final_pass: emit R = 2*Y2 - I as Rt64 +
// bf16-split fragment images. Unchanged.
// =======================================================================
__global__ __launch_bounds__(256, 2)
void kref(const double* __restrict__ M64, const double* __restrict__ Yin,
          double* __restrict__ Yout, double* __restrict__ Rt64,
          unsigned short* __restrict__ img, const int final_pass)
{
  __shared__ double Yc[128][17];
  __shared__ double T[128][17];
  const int t = threadIdx.x;
  const int c0 = blockIdx.x * 16;

  #pragma unroll
  for (int u = 0; u < 8; ++u) {
    int idx = u*256 + t;
    int row = idx >> 4, cc = idx & 15;
    Yc[row][cc] = Yin[row*128 + c0 + cc];
  }
  __syncthreads();

  const int m = t >> 1;
  const int h = (t & 1) * 8;

  double a0=0,a1=0,a2=0,a3=0,a4=0,a5=0,a6=0,a7=0;
  for (int j = 0; j < 128; ++j) {
    double mv = M64[m*128 + j];
    a0 = fma(mv, Yc[j][h+0], a0);  a1 = fma(mv, Yc[j][h+1], a1);
    a2 = fma(mv, Yc[j][h+2], a2);  a3 = fma(mv, Yc[j][h+3], a3);
    a4 = fma(mv, Yc[j][h+4], a4);  a5 = fma(mv, Yc[j][h+5], a5);
    a6 = fma(mv, Yc[j][h+6], a6);  a7 = fma(mv, Yc[j][h+7], a7);
  }
  T[m][h+0]=a0; T[m][h+1]=a1; T[m][h+2]=a2; T[m][h+3]=a3;
  T[m][h+4]=a4; T[m][h+5]=a5; T[m][h+6]=a6; T[m][h+7]=a7;
  __syncthreads();

  double b0=0,b1=0,b2=0,b3=0,b4=0,b5=0,b6=0,b7=0;
  for (int j = 0; j < 128; ++j) {
    double yv = Yin[m*128 + j];
    b0 = fma(yv, T[j][h+0], b0);  b1 = fma(yv, T[j][h+1], b1);
    b2 = fma(yv, T[j][h+2], b2);  b3 = fma(yv, T[j][h+3], b3);
    b4 = fma(yv, T[j][h+4], b4);  b5 = fma(yv, T[j][h+5], b5);
    b6 = fma(yv, T[j][h+6], b6);  b7 = fma(yv, T[j][h+7], b7);
  }

  double y2[8] = { 2.0*Yc[m][h+0]-b0, 2.0*Yc[m][h+1]-b1, 2.0*Yc[m][h+2]-b2,
                   2.0*Yc[m][h+3]-b3, 2.0*Yc[m][h+4]-b4, 2.0*Yc[m][h+5]-b5,
                   2.0*Yc[m][h+6]-b6, 2.0*Yc[m][h+7]-b7 };

  if (!final_pass) {
    #pragma unroll
    for (int c = 0; c < 8; ++c) Yout[m*128 + c0 + h + c] = y2[c];
  } else {
    #pragma unroll
    for (int c = 0; c < 8; ++c) {
      const int i = m, j = c0 + h + c;
      double v = 2.0*y2[c] - ((i == j) ? 1.0 : 0.0);    // R[i][j]
      Rt64[j*128 + i] = v;
      float r32 = (float)v;
      unsigned hh = f2bf(r32);
      unsigned ll = f2bf(r32 - __uint_as_float(hh << 16));
      int off1 = (((i>>5)*8 + (j>>4))*64 + ((((j>>3)&1)<<5) | (i&31)))*8 + (j&7);
      img[off1]          = (unsigned short)hh;
      img[16384 + off1]  = (unsigned short)ll;
      int off2 = (((j>>5)*8 + (i>>4))*64 + ((((i>>3)&1)<<5) | (j&31)))*8 + (i&7);
      img[32768 + off2]  = (unsigned short)hh;
      img[49152 + off2]  = (unsigned short)ll;
    }
  }
}

// =======================================================================
// K_main: round-15 form RESTORED VERBATIM (best measured ~105 us, VGPR
// 128, no spills). Three occupancy pushes (r11/r14/r16) all spilled --
// 2 waves/SIMD is structural for B1+B2-in-regs + 4 f32x16 accumulators
// on the unified VGPR/AGPR file. Do not touch.
// =======================================================================
#define MM3(ACC, XH, XL, BH, BL)                                        \
  ACC = __builtin_amdgcn_mfma_f32_32x32x16_bf16(XH, BH, ACC, 0, 0, 0);  \
  ACC = __builtin_amdgcn_mfma_f32_32x32x16_bf16(XL, BH, ACC, 0, 0, 0);  \
  ACC = __builtin_amdgcn_mfma_f32_32x32x16_bf16(XH, BL, ACC, 0, 0, 0);

#define LGKM_BAR()                                                      \
  asm volatile("s_waitcnt lgkmcnt(0)" ::: "memory");                    \
  __builtin_amdgcn_s_barrier();                                         \
  __builtin_amdgcn_sched_barrier(0);

__global__ __launch_bounds__(256, 2)
void kmain(const float* __restrict__ x, const float* __restrict__ mean,
           const float* __restrict__ cent, const unsigned short* __restrict__ img,
           const float* __restrict__ normg, const float* __restrict__ invg,
           float* __restrict__ out,
           unsigned int* __restrict__ counter, unsigned int* __restrict__ list)
{
  __shared__ __align__(16) unsigned short Xh[2][32*128];
  __shared__ __align__(16) unsigned short Xl[2][32*128];
  __shared__ __align__(16) unsigned short Qh[2][32*128];
  __shared__ __align__(16) unsigned short Ql[2][32*128];
  __shared__ float norms[4][32];     // per-wave private
  __shared__ float invs[4][32];

  const int tid = threadIdx.x, lane = tid & 63, w = tid >> 6;
  const int al = lane & 31, ah = lane >> 5;

  short8 B1h[8], B1l[8], B2h[8], B2l[8];
  #pragma unroll
  for (int t = 0; t < 8; ++t) {
    size_t o = (size_t)((w*8 + t)*64 + lane)*8;
    B1h[t] = *(const short8*)(img +         o);
    B1l[t] = *(const short8*)(img + 16384 + o);
    B2h[t] = *(const short8*)(img + 32768 + o);
    B2l[t] = *(const short8*)(img + 49152 + o);
  }

  const float c0 = cent[0], c1 = cent[1], c2 = cent[2], c3 = cent[3];
  const float c4 = cent[4], c5 = cent[5], c6 = cent[6], c7 = cent[7];
  const float mid0 = 0.5f*(c0+c1), mid1 = 0.5f*(c1+c2), mid2 = 0.5f*(c2+c3),
              mid3 = 0.5f*(c3+c4), mid4 = 0.5f*(c4+c5), mid5 = 0.5f*(c5+c6),
              mid6 = 0.5f*(c6+c7);
  unsigned qt0, qt1, qt2, qt3, qt4, qt5, qt6, qt7;
  {
    #define PS(C, QT) { unsigned h = f2bf(C); float hf = __uint_as_float(h<<16); \
                        QT = (h<<16) | f2bf((C) - hf); }
    PS(c0,qt0) PS(c1,qt1) PS(c2,qt2) PS(c3,qt3)
    PS(c4,qt4) PS(c5,qt5) PS(c6,qt6) PS(c7,qt7)
    #undef PS
  }

  const float2 mean2 = *(const float2*)(mean + 2*lane);
  const float meanv = mean[w*32 + al];

  const int row0 = blockIdx.x * 256;

  float2 xpf[8];
  #pragma unroll
  for (int rr = 0; rr < 8; ++rr)
    xpf[rr] = *(const float2*)(x + (size_t)(row0 + w*8 + rr)*128 + 2*lane);

  for (int ch = 0; ch < 8; ++ch) {
    const int chb = row0 + ch*32;
    const int p = ch & 1;

    // ---- Phase A: next-chunk loads; norm load; cvt_pk split -> X[p] ----
    if (ah == 0) {                         // lanes 0..31: per-wave norm bcast
      norms[w][al] = normg[chb + al];
      invs[w][al]  = invg[chb + al];
    }
    float2 xn[8];
    if (ch < 7) {
      #pragma unroll
      for (int rr = 0; rr < 8; ++rr)
        xn[rr] = *(const float2*)(x + (size_t)(chb + 32 + w*8 + rr)*128 + 2*lane);
    }
    #pragma unroll
    for (int rr = 0; rr < 8; ++rr) {
      const int r = w*8 + rr;
      float a = xpf[rr].x - mean2.x;
      float b = xpf[rr].y - mean2.y;
      unsigned ph, pl;
      asm("v_cvt_pk_bf16_f32 %0, %1, %2" : "=v"(ph) : "v"(a), "v"(b));
      float ha = __uint_as_float(ph << 16);
      float hb = __uint_as_float(ph & 0xFFFF0000u);
      float ra = a - ha, rb = b - hb;
      asm("v_cvt_pk_bf16_f32 %0, %1, %2" : "=v"(pl) : "v"(ra), "v"(rb));
      unsigned off = ((unsigned)(r*256 + 4*lane)) ^ (((unsigned)(r & 7)) << 4);
      *(unsigned*)((char*)&Xh[p][0] + off) = ph;
      *(unsigned*)((char*)&Xl[p][0] + off) = pl;
    }
    #pragma unroll
    for (int rr = 0; rr < 8; ++rr) xpf[rr] = xn[rr];
    LGKM_BAR();                                       // bar1: X[p]+norms ready

    // ---- Phase B: mm1, quantize, write Q[p] ----
    f32x16 accA, accB;
    #pragma unroll
    for (int g = 0; g < 16; ++g) { accA[g] = 0.0f; accB[g] = 0.0f; }
    __builtin_amdgcn_s_setprio(1);
    #pragma unroll
    for (int t = 0; t < 8; ++t) {
      unsigned fb = ((unsigned)(al*256 + t*32 + ah*16)) ^ (((unsigned)(al & 7)) << 4);
      short8 xh = *(const short8*)((const char*)&Xh[p][0] + fb);
      short8 xl = *(const short8*)((const char*)&Xl[p][0] + fb);
      if (t & 1) { MM3(accB, xh, xl, B1h[t], B1l[t]); }
      else       { MM3(accA, xh, xl, B1h[t], B1l[t]); }
    }
    __builtin_amdgcn_s_setprio(0);
    #pragma unroll
    for (int g = 0; g < 16; ++g) accA[g] += accB[g];

    unsigned qp[16];
    unsigned flags = 0;
    #pragma unroll
    for (int g = 0; g < 16; ++g) {
      const int r = (g & 3) + 8*(g >> 2) + 4*ah;
      float xr = accA[g] * invs[w][r];
      unsigned q = qt0;
      q = (xr > mid0) ? qt1 : q;  q = (xr > mid1) ? qt2 : q;
      q = (xr > mid2) ? qt3 : q;  q = (xr > mid3) ? qt4 : q;
      q = (xr > mid4) ? qt5 : q;  q = (xr > mid5) ? qt6 : q;
      q = (xr > mid6) ? qt7 : q;
      float dm = fabsf(xr - mid0);
      dm = fminf(dm, fabsf(xr - mid1)); dm = fminf(dm, fabsf(xr - mid2));
      dm = fminf(dm, fabsf(xr - mid3)); dm = fminf(dm, fabsf(xr - mid4));
      dm = fminf(dm, fabsf(xr - mid5)); dm = fminf(dm, fabsf(xr - mid6));
      qp[g] = q;
      flags |= (dm < MARGIN) ? (1u << g) : 0u;
    }
    #pragma unroll
    for (int g = 0; g < 16; ++g) {
      const int rq = (g & 3) + 8*(g >> 2) + 4*ah;
      unsigned off = ((unsigned)(rq*256 + (w*32 + al)*2)) ^ (((unsigned)(rq & 7)) << 4);
      *(unsigned short*)((char*)&Qh[p][0] + off) = (unsigned short)(qp[g] >> 16);
      *(unsigned short*)((char*)&Ql[p][0] + off) = (unsigned short)(qp[g] & 0xFFFFu);
    }
    if (__builtin_amdgcn_ballot_w64(flags != 0)) {   // rare path
      #pragma unroll
      for (int g = 0; g < 16; ++g) {
        unsigned long long b = __ballot((flags >> g) & 1u);
        if (b) {
          const int rq = (g & 3) + 8*(g >> 2) + 4*ah;
          unsigned base = 0;
          if (lane == 0) base = atomicAdd(counter, (unsigned)__popcll(b));
          base = (unsigned)__shfl((int)base, 0);
          if ((flags >> g) & 1u) {
            unsigned pp = base + (unsigned)__popcll(b & ((1ull << lane) - 1ull));
            if (pp < LIST_CAP) list[pp] = (unsigned)(chb + rq);
          }
        }
      }
    }
    LGKM_BAR();                                       // bar2: Q[p] ready

    // ---- Phase C: mm2 (Q[p] x B2 regs), scale + store ----
    f32x16 acc2, acc3;
    #pragma unroll
    for (int g = 0; g < 16; ++g) { acc2[g] = 0.0f; acc3[g] = 0.0f; }
    __builtin_amdgcn_s_setprio(1);
    #pragma unroll
    for (int t = 0; t < 8; ++t) {
      unsigned fb = ((unsigned)(al*256 + t*32 + ah*16)) ^ (((unsigned)(al & 7)) << 4);
      short8 xh = *(const short8*)((const char*)&Qh[p][0] + fb);
      short8 xl = *(const short8*)((const char*)&Ql[p][0] + fb);
      if (t & 1) { MM3(acc3, xh, xl, B2h[t], B2l[t]); }
      else       { MM3(acc2, xh, xl, B2h[t], B2l[t]); }
    }
    __builtin_amdgcn_s_setprio(0);

    #pragma unroll
    for (int g = 0; g < 16; ++g) {
      const int rq = (g & 3) + 8*(g >> 2) + 4*ah;
      float o = fmaf(acc2[g] + acc3[g], norms[w][rq], meanv);
      out[(size_t)(chb + rq)*128 + w*32 + al] = o;
    }
  }
}

// =======================================================================
// K_fix: exact f64 recompute of rows with any element within MARGIN of
// a quantization midpoint. One wave per row; overwrites out. Unchanged.
// =======================================================================
__global__ __launch_bounds__(256)
void kfix(const float* __restrict__ x, const float* __restrict__ mean,
          const float* __restrict__ cent, const double* __restrict__ Rt64,
          float* __restrict__ out,
          const unsigned int* __restrict__ counter,
          const unsigned int* __restrict__ list)
{
  __shared__ double xs[4][128];
  __shared__ double qs[4][128];
  const int tid = threadIdx.x, lane = tid & 63, w = tid >> 6;

  unsigned cnt = *counter;
  if (cnt > LIST_CAP) cnt = LIST_CAP;

  const double cc0 = (double)cent[0], cc1 = (double)cent[1], cc2 = (double)cent[2],
               cc3 = (double)cent[3], cc4 = (double)cent[4], cc5 = (double)cent[5],
               cc6 = (double)cent[6], cc7 = (double)cent[7];
  const double m0 = 0.5*(cc0+cc1), m1 = 0.5*(cc1+cc2), m2 = 0.5*(cc2+cc3),
               m3 = 0.5*(cc3+cc4), m4 = 0.5*(cc4+cc5), m5 = 0.5*(cc5+cc6),
               m6 = 0.5*(cc6+cc7);

  const unsigned gw = blockIdx.x*4 + w, stride = gridDim.x*4;
  for (unsigned e = gw; e < cnt; e += stride) {
    const int row = (int)list[e];
    const float* xr = x + (size_t)row*128;
    const int j0 = 2*lane;

    double a = (double)xr[j0]   - (double)mean[j0];
    double b = (double)xr[j0+1] - (double)mean[j0+1];
    double s = a*a + b*b;
    s += __shfl_xor(s, 1);  s += __shfl_xor(s, 2);  s += __shfl_xor(s, 4);
    s += __shfl_xor(s, 8);  s += __shfl_xor(s, 16); s += __shfl_xor(s, 32);
    double n = sqrt(s);
    if (n < 1e-8) n = 1e-8;
    double inv = 1.0 / n;
    xs[w][j0]   = a * inv;
    xs[w][j0+1] = b * inv;
    asm volatile("s_waitcnt lgkmcnt(0)" ::: "memory");

    double acc0 = 0.0, acc1 = 0.0;
    for (int j = 0; j < 128; ++j) {
      double xj = xs[w][j];
      acc0 = fma(xj, Rt64[j*128 + j0],     acc0);
      acc1 = fma(xj, Rt64[j*128 + j0 + 1], acc1);
    }
    double q0 = cc0;
    q0 = (acc0 > m0) ? cc1 : q0;  q0 = (acc0 > m1) ? cc2 : q0;
    q0 = (acc0 > m2) ? cc3 : q0;  q0 = (acc0 > m3) ? cc4 : q0;
    q0 = (acc0 > m4) ? cc5 : q0;  q0 = (acc0 > m5) ? cc6 : q0;
    q0 = (acc0 > m6) ? cc7 : q0;
    double q1 = cc0;
    q1 = (acc1 > m0) ? cc1 : q1;  q1 = (acc1 > m1) ? cc2 : q1;
    q1 = (acc1 > m2) ? cc3 : q1;  q1 = (acc1 > m3) ? cc4 : q1;
    q1 = (acc1 > m4) ? cc5 : q1;  q1 = (acc1 > m5) ? cc6 : q1;
    q1 = (acc1 > m6) ? cc7 : q1;
    qs[w][j0]   = q0;
    qs[w][j0+1] = q1;
    asm volatile("s_waitcnt lgkmcnt(0)" ::: "memory");

    double o0 = 0.0, o1 = 0.0;
    for (int k = 0; k < 128; ++k) {
      double qk = qs[w][k];
      o0 = fma(qk, Rt64[j0*128 + k],       o0);
      o1 = fma(qk, Rt64[(j0+1)*128 + k],   o1);
    }
    out[(size_t)row*128 + j0]   = (float)fma(o0, n, (double)mean[j0]);
    out[(size_t)row*128 + j0+1] = (float)fma(o1, n, (double)mean[j0+1]);
  }
}

// =======================================================================
extern "C" void kernel_launch(void* const* d_in, const int* in_sizes, int n_in,
                              void* d_out, int out_size, void* d_ws, size_t ws_size,
                              hipStream_t stream)
{
  (void)in_sizes; (void)n_in; (void)out_size; (void)ws_size;
  const float* x    = (const float*)d_in[0];
  const float* skew = (const float*)d_in[1];
  const float* cent = (const float*)d_in[2];
  const float* mean = (const float*)d_in[3];
  float* out = (float*)d_out;

  char* ws = (char*)d_ws;
  double*         Rt64  = (double*)(ws);
  unsigned short* img   = (unsigned short*)(ws + 131072);
  unsigned int*   cntr  = (unsigned int*)(ws + 262144);
  unsigned int*   list  = (unsigned int*)(ws + 262912);
  double*         M64   = (double*)(ws + 4457216);
  double*         Y64   = (double*)(ws + 4588288);
  double*         Yb    = (double*)(ws + 4719360);
  float*          normg = (float*)(ws + 4850432);
  float*          invg  = (float*)(ws + 5899008);

  kpre <<<dim3(257),  dim3(1024), 0, stream>>>(skew, x, mean, M64, Y64,
                                               normg, invg, cntr);
  kref <<<dim3(8),    dim3(256),  0, stream>>>(M64, Y64, Yb, Rt64, img, 0);
  kref <<<dim3(8),    dim3(256),  0, stream>>>(M64, Yb, Y64, Rt64, img, 1);
  kmain<<<dim3(1024), dim3(256),  0, stream>>>(x, mean, cent, img, normg, invg,
                                               out, cntr, list);
  kfix <<<dim3(256),  dim3(256),  0, stream>>>(x, mean, cent, Rt64, out, cntr, list);
}

// Round 18
// 232.462 us; speedup vs baseline: 1.4858x; 1.1841x over previous
//
#include <hip/hip_runtime.h>

#define BATCH 262144
#define MARGIN 1e-5f
#define LIST_CAP (1u<<20)

typedef __attribute__((ext_vector_type(8))) short short8;
typedef __attribute__((ext_vector_type(16))) float f32x16;

// ---------------- workspace layout (bytes) ----------------
// 0       : Rt64 f64[128][128]  Rt64[j*128+k] = R[k][j]      (131072)
// 131072  : img  u16: i1h[16384] i1l[16384] i2h[16384] i2l[16384] (131072)
// 262144  : counter u32
// 262912  : list u32[LIST_CAP]                                (4 MB)
// 4457216 : M64 f64[128][128]   I+A (exact)                   (131072)
// 4588288 : Y64 f64[128][128]   f32-GJ inverse                (131072)
// 4850432 : normg f32[BATCH]                                  (1048576)
// 5899008 : invg  f32[BATCH]                                  (1048576)

__device__ __forceinline__ unsigned f2bf(float f) {
  unsigned u = __float_as_uint(f);
  return (u + 0x7FFFu + ((u >> 16) & 1u)) >> 16;   // RTN-even bf16
}

// =======================================================================
// K_pre: block 0 = f32 GJ, r15 form VERBATIM (best of 10 variants,
// 114 us: scattered ownership j=s+8e, 2 barriers/iter, in-branch
// single-element colk publish; latency-chain-pinned -- r17's 1-barrier
// merge regressed to 133). Blocks 1..256 fill the bubble with row norms
// (pre-warms L3 with x). Y64 residual ~1e-6; one f64 Newton -> 1e-12.
// =======================================================================
__global__ __attribute__((amdgpu_waves_per_eu(4, 4))) __launch_bounds__(1024)
void kpre(const float* __restrict__ skew, const float* __restrict__ x,
          const float* __restrict__ mean, double* __restrict__ M64,
          double* __restrict__ Y64, float* __restrict__ normg,
          float* __restrict__ invg, unsigned int* __restrict__ counter)
{
  const int tid = threadIdx.x;

  if (blockIdx.x != 0) {
    const int b  = blockIdx.x - 1;
    const int wv = tid >> 6, ln = tid & 63;
    const int rowbase = b*1024 + wv*64;
    const float2 mv = *(const float2*)(mean + 2*ln);
    for (int i = 0; i < 64; ++i) {
      const int row = rowbase + i;
      float2 xv = *(const float2*)(x + (size_t)row*128 + 2*ln);
      float a = xv.x - mv.x, c = xv.y - mv.y;
      float sq = fmaf(a, a, c*c);
      sq += __shfl_xor(sq, 1);  sq += __shfl_xor(sq, 2);  sq += __shfl_xor(sq, 4);
      sq += __shfl_xor(sq, 8);  sq += __shfl_xor(sq, 16); sq += __shfl_xor(sq, 32);
      if (ln == 0) {
        float n = fmaxf(sqrtf(sq), 1e-8f);
        normg[row] = n;
        invg[row]  = 1.0f / n;
      }
    }
    return;
  }

  __shared__ float colk[2][128];
  __shared__ float pivrow[128];
  const int i = tid >> 3;
  const int s = tid & 7;
  if (tid == 0) *counter = 0;

  float M[16];
  #pragma unroll
  for (int e = 0; e < 16; ++e) {
    int j = s + 8*e;
    float v;
    if (i == j)      v = 1.0f;
    else if (i < j)  v =  skew[i*127 - (i*(i-1))/2 + (j - i - 1)];
    else             v = -skew[j*127 - (j*(j-1))/2 + (i - j - 1)];
    M[e] = v;
    M64[i*128 + j] = (double)v;     // exact I+A
  }
  if (s == 0) colk[0][i] = M[0];
  __syncthreads();

  for (int k = 0; k < 128; ++k) {
    const int p = k & 1, np = p ^ 1;
    const int ns = (k + 1) & 7, ne = (k + 1) >> 3;
    if (i == k) {
      float rec = 1.0f / colk[p][k];
      #pragma unroll
      for (int e = 0; e < 16; ++e) {
        int j = s + 8*e;
        float v = (j == k) ? 1.0f : M[e];
        v *= rec;
        M[e] = v;
        pivrow[j] = v;
      }
      if (s == ns && k < 127) colk[np][i] = M[ne];
    }
    __syncthreads();
    if (i != k) {
      float f = colk[p][i];
      #pragma unroll
      for (int e = 0; e < 16; ++e) {
        int j = s + 8*e;
        float v = (j == k) ? 0.0f : M[e];
        M[e] = fmaf(-f, pivrow[j], v);
      }
      if (s == ns && k < 127) colk[np][i] = M[ne];
    }
    __syncthreads();
  }

  #pragma unroll
  for (int e = 0; e < 16; ++e) {
    int j = s + 8*e;
    Y64[i*128 + j] = (double)M[e];
  }
}

// =======================================================================
// K_ref: ONE f64 Newton-Schulz step Y' = Y*(2I - M64*Y) per 16-column
// tile (8 blocks), emitting R = 2*Y' - I as Rt64 + bf16-split images.
// Single pass suffices: f32-GJ residual ~1e-6 -> ~1e-12 after one step,
// far below the bf16-split img floor (~6e-8) and decision-relevant
// scales (expected midpoint flips ~1e-4 over 33.5M elements).
// =======================================================================
__global__ __launch_bounds__(256, 2)
void kref(const double* __restrict__ M64, const double* __restrict__ Yin,
          double* __restrict__ Rt64, unsigned short* __restrict__ img)
{
  __shared__ double Yc[128][17];
  __shared__ double T[128][17];
  const int t = threadIdx.x;
  const int c0 = blockIdx.x * 16;

  #pragma unroll
  for (int u = 0; u < 8; ++u) {
    int idx = u*256 + t;
    int row = idx >> 4, cc = idx & 15;
    Yc[row][cc] = Yin[row*128 + c0 + cc];
  }
  __syncthreads();

  const int m = t >> 1;
  const int h = (t & 1) * 8;

  double a0=0,a1=0,a2=0,a3=0,a4=0,a5=0,a6=0,a7=0;
  for (int j = 0; j < 128; ++j) {
    double mv = M64[m*128 + j];
    a0 = fma(mv, Yc[j][h+0], a0);  a1 = fma(mv, Yc[j][h+1], a1);
    a2 = fma(mv, Yc[j][h+2], a2);  a3 = fma(mv, Yc[j][h+3], a3);
    a4 = fma(mv, Yc[j][h+4], a4);  a5 = fma(mv, Yc[j][h+5], a5);
    a6 = fma(mv, Yc[j][h+6], a6);  a7 = fma(mv, Yc[j][h+7], a7);
  }
  T[m][h+0]=a0; T[m][h+1]=a1; T[m][h+2]=a2; T[m][h+3]=a3;
  T[m][h+4]=a4; T[m][h+5]=a5; T[m][h+6]=a6; T[m][h+7]=a7;
  __syncthreads();

  double b0=0,b1=0,b2=0,b3=0,b4=0,b5=0,b6=0,b7=0;
  for (int j = 0; j < 128; ++j) {
    double yv = Yin[m*128 + j];
    b0 = fma(yv, T[j][h+0], b0);  b1 = fma(yv, T[j][h+1], b1);
    b2 = fma(yv, T[j][h+2], b2);  b3 = fma(yv, T[j][h+3], b3);
    b4 = fma(yv, T[j][h+4], b4);  b5 = fma(yv, T[j][h+5], b5);
    b6 = fma(yv, T[j][h+6], b6);  b7 = fma(yv, T[j][h+7], b7);
  }

  double y2[8] = { 2.0*Yc[m][h+0]-b0, 2.0*Yc[m][h+1]-b1, 2.0*Yc[m][h+2]-b2,
                   2.0*Yc[m][h+3]-b3, 2.0*Yc[m][h+4]-b4, 2.0*Yc[m][h+5]-b5,
                   2.0*Yc[m][h+6]-b6, 2.0*Yc[m][h+7]-b7 };

  #pragma unroll
  for (int c = 0; c < 8; ++c) {
    const int i = m, j = c0 + h + c;
    double v = 2.0*y2[c] - ((i == j) ? 1.0 : 0.0);    // R[i][j]
    Rt64[j*128 + i] = v;
    float r32 = (float)v;
    unsigned hh = f2bf(r32);
    unsigned ll = f2bf(r32 - __uint_as_float(hh << 16));
    int off1 = (((i>>5)*8 + (j>>4))*64 + ((((j>>3)&1)<<5) | (i&31)))*8 + (j&7);
    img[off1]          = (unsigned short)hh;
    img[16384 + off1]  = (unsigned short)ll;
    int off2 = (((j>>5)*8 + (i>>4))*64 + ((((i>>3)&1)<<5) | (j&31)))*8 + (i&7);
    img[32768 + off2]  = (unsigned short)hh;
    img[49152 + off2]  = (unsigned short)ll;
  }
}

// =======================================================================
// K_main: r15/r12 form (best measured ~105 us, VGPR 128, no spills).
// Three occupancy pushes (r11/r14/r16) all spilled -- 2 waves/SIMD is
// structural for B1+B2-in-regs + 4 f32x16 accumulators on the unified
// VGPR/AGPR file. Do not touch.
// =======================================================================
#define MM3(ACC, XH, XL, BH, BL)                                        \
  ACC = __builtin_amdgcn_mfma_f32_32x32x16_bf16(XH, BH, ACC, 0, 0, 0);  \
  ACC = __builtin_amdgcn_mfma_f32_32x32x16_bf16(XL, BH, ACC, 0, 0, 0);  \
  ACC = __builtin_amdgcn_mfma_f32_32x32x16_bf16(XH, BL, ACC, 0, 0, 0);

#define LGKM_BAR()                                                      \
  asm volatile("s_waitcnt lgkmcnt(0)" ::: "memory");                    \
  __builtin_amdgcn_s_barrier();                                         \
  __builtin_amdgcn_sched_barrier(0);

__global__ __launch_bounds__(256, 2)
void kmain(const float* __restrict__ x, const float* __restrict__ mean,
           const float* __restrict__ cent, const unsigned short* __restrict__ img,
           const float* __restrict__ normg, const float* __restrict__ invg,
           float* __restrict__ out,
           unsigned int* __restrict__ counter, unsigned int* __restrict__ list)
{
  __shared__ __align__(16) unsigned short Xh[2][32*128];
  __shared__ __align__(16) unsigned short Xl[2][32*128];
  __shared__ __align__(16) unsigned short Qh[2][32*128];
  __shared__ __align__(16) unsigned short Ql[2][32*128];
  __shared__ float norms[4][32];     // per-wave private
  __shared__ float invs[4][32];

  const int tid = threadIdx.x, lane = tid & 63, w = tid >> 6;
  const int al = lane & 31, ah = lane >> 5;

  short8 B1h[8], B1l[8], B2h[8], B2l[8];
  #pragma unroll
  for (int t = 0; t < 8; ++t) {
    size_t o = (size_t)((w*8 + t)*64 + lane)*8;
    B1h[t] = *(const short8*)(img +         o);
    B1l[t] = *(const short8*)(img + 16384 + o);
    B2h[t] = *(const short8*)(img + 32768 + o);
    B2l[t] = *(const short8*)(img + 49152 + o);
  }

  const float c0 = cent[0], c1 = cent[1], c2 = cent[2], c3 = cent[3];
  const float c4 = cent[4], c5 = cent[5], c6 = cent[6], c7 = cent[7];
  const float mid0 = 0.5f*(c0+c1), mid1 = 0.5f*(c1+c2), mid2 = 0.5f*(c2+c3),
              mid3 = 0.5f*(c3+c4), mid4 = 0.5f*(c4+c5), mid5 = 0.5f*(c5+c6),
              mid6 = 0.5f*(c6+c7);
  unsigned qt0, qt1, qt2, qt3, qt4, qt5, qt6, qt7;
  {
    #define PS(C, QT) { unsigned h = f2bf(C); float hf = __uint_as_float(h<<16); \
                        QT = (h<<16) | f2bf((C) - hf); }
    PS(c0,qt0) PS(c1,qt1) PS(c2,qt2) PS(c3,qt3)
    PS(c4,qt4) PS(c5,qt5) PS(c6,qt6) PS(c7,qt7)
    #undef PS
  }

  const float2 mean2 = *(const float2*)(mean + 2*lane);
  const float meanv = mean[w*32 + al];

  const int row0 = blockIdx.x * 256;

  float2 xpf[8];
  #pragma unroll
  for (int rr = 0; rr < 8; ++rr)
    xpf[rr] = *(const float2*)(x + (size_t)(row0 + w*8 + rr)*128 + 2*lane);

  for (int ch = 0; ch < 8; ++ch) {
    const int chb = row0 + ch*32;
    const int p = ch & 1;

    // ---- Phase A: next-chunk loads; norm load; cvt_pk split -> X[p] ----
    if (ah == 0) {                         // lanes 0..31: per-wave norm bcast
      norms[w][al] = normg[chb + al];
      invs[w][al]  = invg[chb + al];
    }
    float2 xn[8];
    if (ch < 7) {
      #pragma unroll
      for (int rr = 0; rr < 8; ++rr)
        xn[rr] = *(const float2*)(x + (size_t)(chb + 32 + w*8 + rr)*128 + 2*lane);
    }
    #pragma unroll
    for (int rr = 0; rr < 8; ++rr) {
      const int r = w*8 + rr;
      float a = xpf[rr].x - mean2.x;
      float b = xpf[rr].y - mean2.y;
      unsigned ph, pl;
      asm("v_cvt_pk_bf16_f32 %0, %1, %2" : "=v"(ph) : "v"(a), "v"(b));
      float ha = __uint_as_float(ph << 16);
      float hb = __uint_as_float(ph & 0xFFFF0000u);
      float ra = a - ha, rb = b - hb;
      asm("v_cvt_pk_bf16_f32 %0, %1, %2" : "=v"(pl) : "v"(ra), "v"(rb));
      unsigned off = ((unsigned)(r*256 + 4*lane)) ^ (((unsigned)(r & 7)) << 4);
      *(unsigned*)((char*)&Xh[p][0] + off) = ph;
      *(unsigned*)((char*)&Xl[p][0] + off) = pl;
    }
    #pragma unroll
    for (int rr = 0; rr < 8; ++rr) xpf[rr] = xn[rr];
    LGKM_BAR();                                       // bar1: X[p]+norms ready

    // ---- Phase B: mm1, quantize, write Q[p] ----
    f32x16 accA, accB;
    #pragma unroll
    for (int g = 0; g < 16; ++g) { accA[g] = 0.0f; accB[g] = 0.0f; }
    __builtin_amdgcn_s_setprio(1);
    #pragma unroll
    for (int t = 0; t < 8; ++t) {
      unsigned fb = ((unsigned)(al*256 + t*32 + ah*16)) ^ (((unsigned)(al & 7)) << 4);
      short8 xh = *(const short8*)((const char*)&Xh[p][0] + fb);
      short8 xl = *(const short8*)((const char*)&Xl[p][0] + fb);
      if (t & 1) { MM3(accB, xh, xl, B1h[t], B1l[t]); }
      else       { MM3(accA, xh, xl, B1h[t], B1l[t]); }
    }
    __builtin_amdgcn_s_setprio(0);
    #pragma unroll
    for (int g = 0; g < 16; ++g) accA[g] += accB[g];

    unsigned qp[16];
    unsigned flags = 0;
    #pragma unroll
    for (int g = 0; g < 16; ++g) {
      const int r = (g & 3) + 8*(g >> 2) + 4*ah;
      float xr = accA[g] * invs[w][r];
      unsigned q = qt0;
      q = (xr > mid0) ? qt1 : q;  q = (xr > mid1) ? qt2 : q;
      q = (xr > mid2) ? qt3 : q;  q = (xr > mid3) ? qt4 : q;
      q = (xr > mid4) ? qt5 : q;  q = (xr > mid5) ? qt6 : q;
      q = (xr > mid6) ? qt7 : q;
      float dm = fabsf(xr - mid0);
      dm = fminf(dm, fabsf(xr - mid1)); dm = fminf(dm, fabsf(xr - mid2));
      dm = fminf(dm, fabsf(xr - mid3)); dm = fminf(dm, fabsf(xr - mid4));
      dm = fminf(dm, fabsf(xr - mid5)); dm = fminf(dm, fabsf(xr - mid6));
      qp[g] = q;
      flags |= (dm < MARGIN) ? (1u << g) : 0u;
    }
    #pragma unroll
    for (int g = 0; g < 16; ++g) {
      const int rq = (g & 3) + 8*(g >> 2) + 4*ah;
      unsigned off = ((unsigned)(rq*256 + (w*32 + al)*2)) ^ (((unsigned)(rq & 7)) << 4);
      *(unsigned short*)((char*)&Qh[p][0] + off) = (unsigned short)(qp[g] >> 16);
      *(unsigned short*)((char*)&Ql[p][0] + off) = (unsigned short)(qp[g] & 0xFFFFu);
    }
    if (__builtin_amdgcn_ballot_w64(flags != 0)) {   // rare path
      #pragma unroll
      for (int g = 0; g < 16; ++g) {
        unsigned long long b = __ballot((flags >> g) & 1u);
        if (b) {
          const int rq = (g & 3) + 8*(g >> 2) + 4*ah;
          unsigned base = 0;
          if (lane == 0) base = atomicAdd(counter, (unsigned)__popcll(b));
          base = (unsigned)__shfl((int)base, 0);
          if ((flags >> g) & 1u) {
            unsigned pp = base + (unsigned)__popcll(b & ((1ull << lane) - 1ull));
            if (pp < LIST_CAP) list[pp] = (unsigned)(chb + rq);
          }
        }
      }
    }
    LGKM_BAR();                                       // bar2: Q[p] ready

    // ---- Phase C: mm2 (Q[p] x B2 regs), scale + store ----
    f32x16 acc2, acc3;
    #pragma unroll
    for (int g = 0; g < 16; ++g) { acc2[g] = 0.0f; acc3[g] = 0.0f; }
    __builtin_amdgcn_s_setprio(1);
    #pragma unroll
    for (int t = 0; t < 8; ++t) {
      unsigned fb = ((unsigned)(al*256 + t*32 + ah*16)) ^ (((unsigned)(al & 7)) << 4);
      short8 xh = *(const short8*)((const char*)&Qh[p][0] + fb);
      short8 xl = *(const short8*)((const char*)&Ql[p][0] + fb);
      if (t & 1) { MM3(acc3, xh, xl, B2h[t], B2l[t]); }
      else       { MM3(acc2, xh, xl, B2h[t], B2l[t]); }
    }
    __builtin_amdgcn_s_setprio(0);

    #pragma unroll
    for (int g = 0; g < 16; ++g) {
      const int rq = (g & 3) + 8*(g >> 2) + 4*ah;
      float o = fmaf(acc2[g] + acc3[g], norms[w][rq], meanv);
      out[(size_t)(chb + rq)*128 + w*32 + al] = o;
    }
  }
}

// =======================================================================
// K_fix: exact f64 recompute of rows with any element within MARGIN of
// a quantization midpoint. One wave per row; overwrites out. Unchanged.
// =======================================================================
__global__ __launch_bounds__(256)
void kfix(const float* __restrict__ x, const float* __restrict__ mean,
          const float* __restrict__ cent, const double* __restrict__ Rt64,
          float* __restrict__ out,
          const unsigned int* __restrict__ counter,
          const unsigned int* __restrict__ list)
{
  __shared__ double xs[4][128];
  __shared__ double qs[4][128];
  const int tid = threadIdx.x, lane = tid & 63, w = tid >> 6;

  unsigned cnt = *counter;
  if (cnt > LIST_CAP) cnt = LIST_CAP;

  const double cc0 = (double)cent[0], cc1 = (double)cent[1], cc2 = (double)cent[2],
               cc3 = (double)cent[3], cc4 = (double)cent[4], cc5 = (double)cent[5],
               cc6 = (double)cent[6], cc7 = (double)cent[7];
  const double m0 = 0.5*(cc0+cc1), m1 = 0.5*(cc1+cc2), m2 = 0.5*(cc2+cc3),
               m3 = 0.5*(cc3+cc4), m4 = 0.5*(cc4+cc5), m5 = 0.5*(cc5+cc6),
               m6 = 0.5*(cc6+cc7);

  const unsigned gw = blockIdx.x*4 + w, stride = gridDim.x*4;
  for (unsigned e = gw; e < cnt; e += stride) {
    const int row = (int)list[e];
    const float* xr = x + (size_t)row*128;
    const int j0 = 2*lane;

    double a = (double)xr[j0]   - (double)mean[j0];
    double b = (double)xr[j0+1] - (double)mean[j0+1];
    double s = a*a + b*b;
    s += __shfl_xor(s, 1);  s += __shfl_xor(s, 2);  s += __shfl_xor(s, 4);
    s += __shfl_xor(s, 8);  s += __shfl_xor(s, 16); s += __shfl_xor(s, 32);
    double n = sqrt(s);
    if (n < 1e-8) n = 1e-8;
    double inv = 1.0 / n;
    xs[w][j0]   = a * inv;
    xs[w][j0+1] = b * inv;
    asm volatile("s_waitcnt lgkmcnt(0)" ::: "memory");

    double acc0 = 0.0, acc1 = 0.0;
    for (int j = 0; j < 128; ++j) {
      double xj = xs[w][j];
      acc0 = fma(xj, Rt64[j*128 + j0],     acc0);
      acc1 = fma(xj, Rt64[j*128 + j0 + 1], acc1);
    }
    double q0 = cc0;
    q0 = (acc0 > m0) ? cc1 : q0;  q0 = (acc0 > m1) ? cc2 : q0;
    q0 = (acc0 > m2) ? cc3 : q0;  q0 = (acc0 > m3) ? cc4 : q0;
    q0 = (acc0 > m4) ? cc5 : q0;  q0 = (acc0 > m5) ? cc6 : q0;
    q0 = (acc0 > m6) ? cc7 : q0;
    double q1 = cc0;
    q1 = (acc1 > m0) ? cc1 : q1;  q1 = (acc1 > m1) ? cc2 : q1;
    q1 = (acc1 > m2) ? cc3 : q1;  q1 = (acc1 > m3) ? cc4 : q1;
    q1 = (acc1 > m4) ? cc5 : q1;  q1 = (acc1 > m5) ? cc6 : q1;
    q1 = (acc1 > m6) ? cc7 : q1;
    qs[w][j0]   = q0;
    qs[w][j0+1] = q1;
    asm volatile("s_waitcnt lgkmcnt(0)" ::: "memory");

    double o0 = 0.0, o1 = 0.0;
    for (int k = 0; k < 128; ++k) {
      double qk = qs[w][k];
      o0 = fma(qk, Rt64[j0*128 + k],       o0);
      o1 = fma(qk, Rt64[(j0+1)*128 + k],   o1);
    }
    out[(size_t)row*128 + j0]   = (float)fma(o0, n, (double)mean[j0]);
    out[(size_t)row*128 + j0+1] = (float)fma(o1, n, (double)mean[j0+1]);
  }
}

// =======================================================================
extern "C" void kernel_launch(void* const* d_in, const int* in_sizes, int n_in,
                              void* d_out, int out_size, void* d_ws, size_t ws_size,
                              hipStream_t stream)
{
  (void)in_sizes; (void)n_in; (void)out_size; (void)ws_size;
  const float* x    = (const float*)d_in[0];
  const float* skew = (const float*)d_in[1];
  const float* cent = (const float*)d_in[2];
  const float* mean = (const float*)d_in[3];
  float* out = (float*)d_out;

  char* ws = (char*)d_ws;
  double*         Rt64  = (double*)(ws);
  unsigned short* img   = (unsigned short*)(ws + 131072);
  unsigned int*   cntr  = (unsigned int*)(ws + 262144);
  unsigned int*   list  = (unsigned int*)(ws + 262912);
  double*         M64   = (double*)(ws + 4457216);
  double*         Y64   = (double*)(ws + 4588288);
  float*          normg = (float*)(ws + 4850432);
  float*          invg  = (float*)(ws + 5899008);

  kpre <<<dim3(257),  dim3(1024), 0, stream>>>(skew, x, mean, M64, Y64,
                                               normg, invg, cntr);
  kref <<<dim3(8),    dim3(256),  0, stream>>>(M64, Y64, Rt64, img);
  kmain<<<dim3(1024), dim3(256),  0, stream>>>(x, mean, cent, img, normg, invg,
                                               out, cntr, list);
  kfix <<<dim3(256),  dim3(256),  0, stream>>>(x, mean, cent, Rt64, out, cntr, list);
}